// Round 10
// baseline (28100.021 us; speedup 1.0000x reference)
//
#include <hip/hip_runtime.h>
#include <math.h>

// PGJANET persistent kernel, round 10: ONE hop/step, fp32, precise libm.
// 64 batch-groups (MB=2 batches) x 4 col-slice WGs (64 cols), grid 256
// (1 WG/CU guaranteed), 512 thr. Per step: S1 for own 64 cols -> u (local);
// stage-2 PARTIALS over own 128 W2-rows (64 u-rows + 64 h-rows) for ALL 256
// cols; publish partials as self-validating {p_b0,p_b1,seq,0} 16B chunks
// (transaction-atomic dwordx4, sc0 sc1), DOUBLE-BUFFERED by t-parity; each
// thread polls its 4 producer chunks (one IC trip); fixed-order sum;
// replicated precise epilogue -> bit-identical h(t+1) in all 4 WGs of the
// group. No h exchange, no sentinels, no cache maintenance.
// Weights fp32 in VGPRs: W1 96 + W2-slice 128 regs/thread.

#define B_    128
#define T_    1024
#define H_    256
#define GB    64
#define GC    4
#define MB    2
#define NCOL  64
#define NTHR  512
#define HP    260              // h_lds row stride (floats); 1040B, 16B-aligned
#define WGU32 2048             // uints per WG region (512 chunks * 4)
#define BUFU32 (256 * WGU32)   // uints per t-parity buffer (2 MB)

typedef float    f32x4 __attribute__((ext_vector_type(4)));
typedef unsigned u32x4 __attribute__((ext_vector_type(4)));

__device__ __forceinline__ void sys_st_x4(unsigned* p, u32x4 v) {
  asm volatile("global_store_dwordx4 %0, %1, off sc0 sc1" :: "v"(p), "v"(v) : "memory");
}
__device__ __forceinline__ void sys_ld4_x4(const unsigned* p0, const unsigned* p1,
                                           const unsigned* p2, const unsigned* p3,
                                           u32x4& a, u32x4& b, u32x4& c, u32x4& d) {
  asm volatile("global_load_dwordx4 %0, %4, off sc0 sc1\n\t"
               "global_load_dwordx4 %1, %5, off sc0 sc1\n\t"
               "global_load_dwordx4 %2, %6, off sc0 sc1\n\t"
               "global_load_dwordx4 %3, %7, off sc0 sc1\n\t"
               "s_waitcnt vmcnt(0)"
               : "=&v"(a), "=&v"(b), "=&v"(c), "=&v"(d)
               : "v"(p0), "v"(p1), "v"(p2), "v"(p3) : "memory");
}

__launch_bounds__(NTHR, 2)   // cap VGPR at 256 (8 waves = 2/SIMD resident)
__global__ void pgjanet_persist(
    const float* __restrict__ x,   const float* __restrict__ h0,
    const float* __restrict__ Wa,  const float* __restrict__ ba,
    const float* __restrict__ Wp1, const float* __restrict__ bp1,
    const float* __restrict__ Wp2, const float* __restrict__ bp2,
    const float* __restrict__ Wz,  const float* __restrict__ bz,
    const float* __restrict__ Wh,  const float* __restrict__ bh,
    const float* __restrict__ Wo,  const float* __restrict__ bo,
    float* __restrict__ out,        // [B*T*2] then h_n [B*H]
    unsigned* __restrict__ pex)     // [2][256 WGs][512 chunks * 4 uints]
{
  __shared__ __align__(16) float h_lds[MB][HP];      // replicated full h
  __shared__ __align__(16) float u_lds[MB][NCOL];    // own-slice u
  __shared__ __align__(16) float pre_s[2][H_][MB];   // summed preacts
  __shared__ __align__(16) float wo_s[H_ * 2];
  __shared__ __align__(16) float xin[2][MB][4];      // {amp,cos,sin,0} dbuf

  const int wg    = blockIdx.x;
  const int g     = wg >> 2;
  const int gc    = wg & 3;
  const int tid   = threadIdx.x;
  const int c1    = tid >> 3;       // S1 col 0..63 (within slice)
  const int ks    = tid & 7;        // S1 k-lane (8-way)
  const int M     = tid >> 8;       // P: matrix 0=z 1=hc
  const int n     = tid & 255;      // P: global col
  const int nE    = tid >> 1;       // epilogue col
  const int bE    = tid & 1;        // epilogue batch
  const int b0    = g * MB;
  const int gcol0 = gc * NCOL;
  const int colg1 = gcol0 + c1;

  // ---- one-time: hoist fp32 weights into VGPRs ----
  // S1 weights: k = ks*4 + j*32 + c (j 0..7) for own col colg1
  f32x4 w1r[3][8]; float w1r0_[3], b1_[3];
#pragma unroll
  for (int m = 0; m < 3; ++m) {
    const float* W  = (m == 0) ? Wa : (m == 1 ? Wp1 : Wp2);
    const float* bb = (m == 0) ? ba : (m == 1 ? bp1 : bp2);
#pragma unroll
    for (int j = 0; j < 8; ++j) {
      f32x4 w;
#pragma unroll
      for (int c = 0; c < 4; ++c)
        w[c] = W[(1 + ks * 4 + j * 32 + c) * H_ + colg1];
      w1r[m][j] = w;
    }
    w1r0_[m] = W[colg1];
    b1_[m]   = bb[colg1];
  }
  // P weights: part p=0 -> u-rows gcol0+j*4+c; p=1 -> h-rows 256+gcol0+j*4+c
  f32x4 w2p[2][16];
  {
    const float* WM = (M == 0) ? Wz : Wh;
#pragma unroll
    for (int p = 0; p < 2; ++p)
#pragma unroll
      for (int j = 0; j < 16; ++j) {
        f32x4 w;
#pragma unroll
        for (int c = 0; c < 4; ++c)
          w[c] = WM[(p * H_ + gcol0 + j * 4 + c) * H_ + n];
        w2p[p][j] = w;
      }
  }
  const float bz_e = bz[nE], bh_e = bh[nE];
  const float bo0 = bo[0], bo1 = bo[1];
  for (int i = tid; i < H_ * 2; i += NTHR) wo_s[i] = Wo[i];
  if (tid < 128) {
    int b = tid >> 6, k4 = (tid & 63) * 4;
    *(f32x4*)&h_lds[b][k4] = *(const f32x4*)(h0 + (size_t)(b0 + b) * H_ + k4);
  }
  if (tid < MB) {
    float2 xt = *(const float2*)(x + ((size_t)(b0 + tid) * T_) * 2);
    xin[0][tid][0] = xt.x; xin[0][tid][1] = cosf(xt.y);
    xin[0][tid][2] = sinf(xt.y); xin[0][tid][3] = 0.f;
  }
  __syncthreads();

  unsigned* pub0 = pex + (size_t)wg * WGU32;            // buf0 publish base
  unsigned* pub1 = pex + BUFU32 + (size_t)wg * WGU32;   // buf1
  const unsigned* cons0 = pex + (size_t)(g * GC) * WGU32;
  const unsigned* cons1 = pex + BUFU32 + (size_t)(g * GC) * WGU32;

  for (int t = 0; t < T_; ++t) {
    const unsigned seq = (unsigned)(t + 1);
    const int xb = t & 1;

    // ---- S1: 3 mats x own col x 2 batches over K=256 (weights in regs) ----
    float acc[6];
#pragma unroll
    for (int i = 0; i < 6; ++i) acc[i] = 0.f;
#pragma unroll
    for (int b = 0; b < MB; ++b) {
#pragma unroll
      for (int j = 0; j < 8; ++j) {
        f32x4 h4 = *(const f32x4*)&h_lds[b][ks * 4 + j * 32];
#pragma unroll
        for (int m = 0; m < 3; ++m) {
          float s = acc[m * 2 + b];
          s = fmaf(h4[0], w1r[m][j][0], s); s = fmaf(h4[1], w1r[m][j][1], s);
          s = fmaf(h4[2], w1r[m][j][2], s); s = fmaf(h4[3], w1r[m][j][3], s);
          acc[m * 2 + b] = s;
        }
      }
    }
#pragma unroll
    for (int i = 0; i < 6; ++i) {
      float v = acc[i];
      v += __shfl_xor(v, 1); v += __shfl_xor(v, 2); v += __shfl_xor(v, 4);
      acc[i] = v;
    }
    // ---- S1 epilogue, lane-parallel: ks<6 -> (mat ks>>1, batch ks&1) ----
    {
      int m = ks >> 1, b = ks & 1;
      float pre1 = acc[0];
      pre1 = (ks == 1) ? acc[1] : pre1;
      pre1 = (ks == 2) ? acc[2] : pre1;
      pre1 = (ks == 3) ? acc[3] : pre1;
      pre1 = (ks == 4) ? acc[4] : pre1;
      pre1 = (ks == 5) ? acc[5] : pre1;
      float w0  = (m == 0) ? w1r0_[0] : ((m == 1) ? w1r0_[1] : w1r0_[2]);
      float bb1 = (m == 0) ? b1_[0]   : ((m == 1) ? b1_[1]   : b1_[2]);
      f32x4 xi  = *(const f32x4*)&xin[xb][b][0];
      float xim = (m == 0) ? xi[0] : ((m == 1) ? xi[1] : xi[2]);
      float tv  = tanhf(pre1 + xim * w0 + bb1);     // a / p1 / p2 per role
      float p1v = __shfl(tv, ks + 2, 8);
      float p2v = __shfl(tv, ks + 4, 8);
      if (ks < 2) {
        float uv = tv * p1v * p2v * (1.f - tv) * (1.f - p1v) * (1.f - p2v);
        u_lds[b][c1] = uv;
      }
    }
    __syncthreads();                                 // B1: u_lds ready

    // ---- P: partials over own 128 W2-rows for col n, both batches ----
    float pa[2];
#pragma unroll
    for (int b = 0; b < MB; ++b) {
      float s = 0.f;
#pragma unroll
      for (int j = 0; j < 16; ++j) {                 // u-rows (broadcast reads)
        f32x4 u4 = *(const f32x4*)&u_lds[b][j * 4];
        s = fmaf(u4[0], w2p[0][j][0], s); s = fmaf(u4[1], w2p[0][j][1], s);
        s = fmaf(u4[2], w2p[0][j][2], s); s = fmaf(u4[3], w2p[0][j][3], s);
      }
#pragma unroll
      for (int j = 0; j < 16; ++j) {                 // h-rows
        f32x4 h4 = *(const f32x4*)&h_lds[b][gcol0 + j * 4];
        s = fmaf(h4[0], w2p[1][j][0], s); s = fmaf(h4[1], w2p[1][j][1], s);
        s = fmaf(h4[2], w2p[1][j][2], s); s = fmaf(h4[3], w2p[1][j][3], s);
      }
      pa[b] = s;
    }
    // ---- publish own chunk (coalesced 8KB/WG), dbuf by t-parity ----
    {
      u32x4 ch;
      ch.x = __float_as_uint(pa[0]); ch.y = __float_as_uint(pa[1]);
      ch.z = seq; ch.w = 0u;
      sys_st_x4((xb ? pub1 : pub0) + tid * 4, ch);
    }

    // ---- hop-window covers: out-GEMV for row t-1 + x(t+1) prefetch ----
    if (t > 0 && ((t - 1) & 3) == gc && tid < 128) {
      int b = tid >> 6, l = tid & 63;
      f32x4 h4  = *(const f32x4*)&h_lds[b][l * 4];
      f32x4 wo0 = *(const f32x4*)&wo_s[l * 8];
      f32x4 wo1 = *(const f32x4*)&wo_s[l * 8 + 4];
      float v0 = h4[0] * wo0[0] + h4[1] * wo0[2] + h4[2] * wo1[0] + h4[3] * wo1[2];
      float v1 = h4[0] * wo0[1] + h4[1] * wo0[3] + h4[2] * wo1[1] + h4[3] * wo1[3];
      v0 += __shfl_xor(v0, 1);  v1 += __shfl_xor(v1, 1);
      v0 += __shfl_xor(v0, 2);  v1 += __shfl_xor(v1, 2);
      v0 += __shfl_xor(v0, 4);  v1 += __shfl_xor(v1, 4);
      v0 += __shfl_xor(v0, 8);  v1 += __shfl_xor(v1, 8);
      v0 += __shfl_xor(v0, 16); v1 += __shfl_xor(v1, 16);
      v0 += __shfl_xor(v0, 32); v1 += __shfl_xor(v1, 32);
      if (l == 0) {
        float2 o; o.x = v0 + bo0; o.y = v1 + bo1;
        *(float2*)(out + ((size_t)(b0 + b) * T_ + (t - 1)) * 2) = o;
      }
    }
    if (t + 1 < T_ && tid < MB) {
      float2 xt = *(const float2*)(x + ((size_t)(b0 + tid) * T_ + (t + 1)) * 2);
      xin[xb ^ 1][tid][0] = xt.x; xin[xb ^ 1][tid][1] = cosf(xt.y);
      xin[xb ^ 1][tid][2] = sinf(xt.y); xin[xb ^ 1][tid][3] = 0.f;
    }

    // ---- ONE hop: poll own chunk from each of 4 producers ----
    {
      const unsigned* cb = xb ? cons1 : cons0;
      const unsigned* p0 = cb + 0 * WGU32 + tid * 4;
      const unsigned* p1 = cb + 1 * WGU32 + tid * 4;
      const unsigned* p2 = cb + 2 * WGU32 + tid * 4;
      const unsigned* p3 = cb + 3 * WGU32 + tid * 4;
      u32x4 A, Bq, Cq, Dq;
      for (;;) {
        sys_ld4_x4(p0, p1, p2, p3, A, Bq, Cq, Dq);
        if (A.z == seq && Bq.z == seq && Cq.z == seq && Dq.z == seq) break;
        __builtin_amdgcn_s_sleep(1);
      }
      // fixed-order sum -> identical bits in all 4 consumer WGs
      float s0 = (__uint_as_float(A.x) + __uint_as_float(Bq.x)) +
                 (__uint_as_float(Cq.x) + __uint_as_float(Dq.x));
      float s1 = (__uint_as_float(A.y) + __uint_as_float(Bq.y)) +
                 (__uint_as_float(Cq.y) + __uint_as_float(Dq.y));
      float2 pv; pv.x = s0; pv.y = s1;
      *(float2*)&pre_s[M][n][0] = pv;
    }
    __syncthreads();                                 // B2: preacts ready

    // ---- replicated epilogue: h(t+1), bit-identical across the group ----
    {
      float z  = 1.f / (1.f + expf(-(pre_s[0][nE][bE] + bz_e)));
      float hc = tanhf(pre_s[1][nE][bE] + bh_e);
      float hn = z * h_lds[bE][nE] + (1.f - z) * hc;
      h_lds[bE][nE] = hn;
      if (t == T_ - 1 && gc == 0)
        out[(size_t)B_ * T_ * 2 + (size_t)(b0 + bE) * H_ + nE] = hn;   // h_n
    }
    __syncthreads();                                 // B3: h(t+1) ready
  }

  // ---- tail: out[:, T-1] from h(T) ----
  if (gc == 1 && tid < 128) {
    int b = tid >> 6, l = tid & 63;
    f32x4 h4  = *(const f32x4*)&h_lds[b][l * 4];
    f32x4 wo0 = *(const f32x4*)&wo_s[l * 8];
    f32x4 wo1 = *(const f32x4*)&wo_s[l * 8 + 4];
    float v0 = h4[0] * wo0[0] + h4[1] * wo0[2] + h4[2] * wo1[0] + h4[3] * wo1[2];
    float v1 = h4[0] * wo0[1] + h4[1] * wo0[3] + h4[2] * wo1[1] + h4[3] * wo1[3];
    v0 += __shfl_xor(v0, 1);  v1 += __shfl_xor(v1, 1);
    v0 += __shfl_xor(v0, 2);  v1 += __shfl_xor(v1, 2);
    v0 += __shfl_xor(v0, 4);  v1 += __shfl_xor(v1, 4);
    v0 += __shfl_xor(v0, 8);  v1 += __shfl_xor(v1, 8);
    v0 += __shfl_xor(v0, 16); v1 += __shfl_xor(v1, 16);
    v0 += __shfl_xor(v0, 32); v1 += __shfl_xor(v1, 32);
    if (l == 0) {
      float2 o; o.x = v0 + bo0; o.y = v1 + bo1;
      *(float2*)(out + ((size_t)(b0 + b) * T_ + (T_ - 1)) * 2) = o;
    }
  }
}

extern "C" void kernel_launch(void* const* d_in, const int* in_sizes, int n_in,
                              void* d_out, int out_size, void* d_ws, size_t ws_size,
                              hipStream_t stream) {
  (void)in_sizes; (void)n_in; (void)out_size; (void)ws_size;
  const float* x   = (const float*)d_in[0];
  const float* h0  = (const float*)d_in[1];
  const float* Wa  = (const float*)d_in[2];
  const float* ba  = (const float*)d_in[3];
  const float* Wp1 = (const float*)d_in[4];
  const float* bp1 = (const float*)d_in[5];
  const float* Wp2 = (const float*)d_in[6];
  const float* bp2 = (const float*)d_in[7];
  const float* Wz  = (const float*)d_in[8];
  const float* bz  = (const float*)d_in[9];
  const float* Wh  = (const float*)d_in[10];
  const float* bh  = (const float*)d_in[11];
  const float* Wo  = (const float*)d_in[12];
  const float* bo  = (const float*)d_in[13];

  float*    out = (float*)d_out;
  unsigned* pex = (unsigned*)d_ws;     // 2 bufs x 256 WGs x 8KB = 4 MB

  // seqs restart at 1 each replay; zero both partial buffers so no chunk can
  // spuriously match (exact == check makes this belt-and-braces, but cheap).
  hipMemsetAsync(d_ws, 0, 2 * (size_t)BUFU32 * 4, stream);

  pgjanet_persist<<<dim3(GB * GC), dim3(NTHR), 0, stream>>>(
      x, h0, Wa, ba, Wp1, bp1, Wp2, bp2, Wz, bz, Wh, bh, Wo, bo, out, pex);
}

// Round 12
// 5878.905 us; speedup vs baseline: 4.7798x; 4.7798x over previous
//
#include <hip/hip_runtime.h>
#include <math.h>

// PGJANET persistent kernel, round 12 = round 11 with the `bh` name-collision
// fixed (local batch-half renamed bhlf; it had collided with the bias param).
// r4's proven exchange protocol + weights hoisted to VGPRs + precise libm.
// 16 batch-groups (MB=8) x 16 col-slice WGs (16 cols), 512 thr, grid 256.

#define B_   128
#define T_   1024
#define H_   256
#define GB   16
#define GC   16
#define MB   8
#define NTHR 512
#define HPAD 264   // 264%32==8 -> benign aliasing for f32x4 row reads

typedef float    f32x4 __attribute__((ext_vector_type(4)));
typedef unsigned u32x4 __attribute__((ext_vector_type(4)));

__device__ __forceinline__ void sys_st_x4(unsigned* p, u32x4 v) {
  asm volatile("global_store_dwordx4 %0, %1, off sc0 sc1" :: "v"(p), "v"(v) : "memory");
}
__device__ __forceinline__ void sys_ld2_x4(const unsigned* p0, const unsigned* p1,
                                           u32x4& a, u32x4& b) {
  asm volatile("global_load_dwordx4 %0, %2, off sc0 sc1\n\t"
               "global_load_dwordx4 %1, %3, off sc0 sc1\n\t"
               "s_waitcnt vmcnt(0)"
               : "=&v"(a), "=&v"(b) : "v"(p0), "v"(p1) : "memory");
}

__launch_bounds__(NTHR, 1)
__global__ void pgjanet_persist(
    const float* __restrict__ x,   const float* __restrict__ h0,
    const float* __restrict__ Wa,  const float* __restrict__ ba,
    const float* __restrict__ Wp1, const float* __restrict__ bp1,
    const float* __restrict__ Wp2, const float* __restrict__ bp2,
    const float* __restrict__ Wz,  const float* __restrict__ bz,
    const float* __restrict__ Wh,  const float* __restrict__ bh,
    const float* __restrict__ Wo,  const float* __restrict__ bo,
    float* __restrict__ out,        // [B*T*2] then h_n [B*H]
    unsigned* __restrict__ u_ex,    // [GB][1024 chunks * 4 uints]
    unsigned* __restrict__ h_ex)    // [GB][1024 chunks * 4 uints]
{
  __shared__ __align__(16) float h_lds[MB * HPAD];   // 8.25 KB
  __shared__ __align__(16) float u_lds[MB * HPAD];   // 8.25 KB
  __shared__ __align__(16) float wo_s[H_ * 2];       // 2 KB
  __shared__ __align__(16) float xin[2][MB][4];      // {amp,cos,sin,0} dbuf

  const int wg   = blockIdx.x;
  const int g    = wg >> 4;
  const int gc   = wg & 15;
  const int tid  = threadIdx.x;
  const int lane = tid & 63;
  const int w    = tid >> 6;           // wave 0..7, owns cols {2w, 2w+1}
  const int kl   = lane & 15;          // 16-way k-split lane
  const int bhlf = (lane >> 4) & 1;    // batch half (0: b0-3, 1: b4-7)
  const int cp   = (lane >> 5) & 1;    // col parity within the wave's pair
  const int col  = w * 2 + cp;         // 0..15
  const int colg = gc * 16 + col;      // global column
  const int b0   = g * MB;

  // ---- one-time: hoist all fp32 weights into VGPRs (static indices) ----
  // S1: k = kl*4 + j*64 + c  (16 k/thread)
  f32x4 w1r[3][4]; float w1r0_[3], b1_[3];
#pragma unroll
  for (int m = 0; m < 3; ++m) {
    const float* W  = (m == 0) ? Wa : (m == 1 ? Wp1 : Wp2);
    const float* bb = (m == 0) ? ba : (m == 1 ? bp1 : bp2);
#pragma unroll
    for (int j = 0; j < 4; ++j) {
      f32x4 v;
#pragma unroll
      for (int c = 0; c < 4; ++c)
        v[c] = W[(1 + kl * 4 + j * 64 + c) * H_ + colg];
      w1r[m][j] = v;
    }
    w1r0_[m] = W[colg];
    b1_[m]   = bb[colg];
  }
  // S2: K=512=[u(0..255), h(256..511)]; j<4 -> u rows, j>=4 -> h rows
  f32x4 w2r[2][8];
#pragma unroll
  for (int m = 0; m < 2; ++m) {
    const float* W = (m == 0) ? Wz : Wh;
#pragma unroll
    for (int j = 0; j < 8; ++j) {
      int rb = (j < 4) ? (kl * 4 + j * 64) : (256 + kl * 4 + (j - 4) * 64);
      f32x4 v;
#pragma unroll
      for (int c = 0; c < 4; ++c)
        v[c] = W[(rb + c) * H_ + colg];
      w2r[m][j] = v;
    }
  }
  const float bz_c = bz[colg], bh_c = bh[colg];
  const float bo0 = bo[0], bo1 = bo[1];
  for (int i = tid; i < H_ * 2; i += NTHR) wo_s[i] = Wo[i];
  {
    int row = tid >> 6, k4 = (tid & 63) * 4;
    *(f32x4*)&h_lds[row * HPAD + k4] =
        *(const f32x4*)(h0 + (size_t)(b0 + row) * H_ + k4);
  }
  if (tid < MB) {
    float2 xt = *(const float2*)(x + ((size_t)(b0 + tid) * T_) * 2);
    xin[0][tid][0] = xt.x; xin[0][tid][1] = cosf(xt.y);
    xin[0][tid][2] = sinf(xt.y); xin[0][tid][3] = 0.f;
  }
  __syncthreads();

  unsigned* u_exg = u_ex + g * 4096;    // 1024 chunks * 4 uints per group
  unsigned* h_exg = h_ex + g * 4096;
  unsigned* u_my  = u_exg + ((gc * 8 + w) * 8) * 4;   // + b*4 at store
  unsigned* h_my  = h_exg + ((gc * 8 + w) * 8) * 4;
  const unsigned* pu0 = u_exg + tid * 4;              // consumer chunks
  const unsigned* pu1 = u_exg + (tid + 512) * 4;
  const unsigned* ph0 = h_exg + tid * 4;
  const unsigned* ph1 = h_exg + (tid + 512) * 4;

  for (int t = 0; t < T_; ++t) {
    const unsigned seq = (unsigned)(t + 1);
    const int xb = t & 1;

    // ---- S1: 3 mats x own col x 4 batches (weights in regs) ----
    float acc[12];
#pragma unroll
    for (int i = 0; i < 12; ++i) acc[i] = 0.f;
#pragma unroll
    for (int bb = 0; bb < 4; ++bb) {
      const float* hr = &h_lds[(bhlf * 4 + bb) * HPAD];
#pragma unroll
      for (int j = 0; j < 4; ++j) {
        f32x4 h4 = *(const f32x4*)(hr + kl * 4 + j * 64);
#pragma unroll
        for (int m = 0; m < 3; ++m) {
          float s = acc[m * 4 + bb];
          s = fmaf(h4[0], w1r[m][j][0], s); s = fmaf(h4[1], w1r[m][j][1], s);
          s = fmaf(h4[2], w1r[m][j][2], s); s = fmaf(h4[3], w1r[m][j][3], s);
          acc[m * 4 + bb] = s;
        }
      }
    }
#pragma unroll
    for (int i = 0; i < 12; ++i) {
      float v = acc[i];
      v += __shfl_xor(v, 1); v += __shfl_xor(v, 2);
      v += __shfl_xor(v, 4); v += __shfl_xor(v, 8);
      acc[i] = v;
    }
    // ---- S1 epilogue (lane-parallel, precise libm) + per-wave publish ----
    {
      float pre1 = acc[0];
      pre1 = (kl == 1)  ? acc[1]  : pre1;  pre1 = (kl == 2)  ? acc[2]  : pre1;
      pre1 = (kl == 3)  ? acc[3]  : pre1;  pre1 = (kl == 4)  ? acc[4]  : pre1;
      pre1 = (kl == 5)  ? acc[5]  : pre1;  pre1 = (kl == 6)  ? acc[6]  : pre1;
      pre1 = (kl == 7)  ? acc[7]  : pre1;  pre1 = (kl == 8)  ? acc[8]  : pre1;
      pre1 = (kl == 9)  ? acc[9]  : pre1;  pre1 = (kl == 10) ? acc[10] : pre1;
      pre1 = (kl == 11) ? acc[11] : pre1;
      int m = kl >> 2;                 // 0=a, 1=p1, 2=p2 (kl<12)
      int batch = bhlf * 4 + (kl & 3);
      float w0  = (m == 0) ? w1r0_[0] : ((m == 1) ? w1r0_[1] : w1r0_[2]);
      float bb1 = (m == 0) ? b1_[0]   : ((m == 1) ? b1_[1]   : b1_[2]);
      float xam = xin[xb][batch][0], xcs = xin[xb][batch][1], xsn = xin[xb][batch][2];
      float xim = (m == 0) ? xam : ((m == 1) ? xcs : xsn);
      float tv  = tanhf(pre1 + xim * w0 + bb1);
      float p1v = __shfl(tv, kl + 4, 16);
      float p2v = __shfl(tv, kl + 8, 16);
      float uv  = tv * p1v * p2v * (1.f - tv) * (1.f - p1v) * (1.f - p2v);
      float uodd = __shfl_xor(uv, 32);               // partner col
      if (lane < 32 && kl < 4) {
        u32x4 ch;
        ch.x = __float_as_uint(uv); ch.y = __float_as_uint(uodd);
        ch.z = seq; ch.w = 0u;
        sys_st_x4(u_my + (bhlf * 4 + kl) * 4, ch);
      }
    }

    // ---- u-hop covers: x prefetch, out-GEMV, S2 h-part ----
    if (t + 1 < T_ && tid < MB) {
      float2 xt = *(const float2*)(x + ((size_t)(b0 + tid) * T_ + (t + 1)) * 2);
      xin[xb ^ 1][tid][0] = xt.x; xin[xb ^ 1][tid][1] = cosf(xt.y);
      xin[xb ^ 1][tid][2] = sinf(xt.y); xin[xb ^ 1][tid][3] = 0.f;
    }
    if (t > 0 && ((t - 1) & 15) == gc) {   // out[t-1] = h(t) @ Wo + bo
      f32x4 h4  = *(const f32x4*)&h_lds[w * HPAD + lane * 4];
      f32x4 wo0 = *(const f32x4*)&wo_s[lane * 8];
      f32x4 wo1 = *(const f32x4*)&wo_s[lane * 8 + 4];
      float v0 = h4[0] * wo0[0] + h4[1] * wo0[2] + h4[2] * wo1[0] + h4[3] * wo1[2];
      float v1 = h4[0] * wo0[1] + h4[1] * wo0[3] + h4[2] * wo1[1] + h4[3] * wo1[3];
      v0 += __shfl_xor(v0, 1);  v1 += __shfl_xor(v1, 1);
      v0 += __shfl_xor(v0, 2);  v1 += __shfl_xor(v1, 2);
      v0 += __shfl_xor(v0, 4);  v1 += __shfl_xor(v1, 4);
      v0 += __shfl_xor(v0, 8);  v1 += __shfl_xor(v1, 8);
      v0 += __shfl_xor(v0, 16); v1 += __shfl_xor(v1, 16);
      v0 += __shfl_xor(v0, 32); v1 += __shfl_xor(v1, 32);
      if (lane == 0) {
        float2 o; o.x = v0 + bo0; o.y = v1 + bo1;
        *(float2*)(out + ((size_t)(b0 + w) * T_ + (t - 1)) * 2) = o;
      }
    }
    float acc2[8];
#pragma unroll
    for (int i = 0; i < 8; ++i) acc2[i] = 0.f;
#pragma unroll
    for (int bb = 0; bb < 4; ++bb) {
      const float* hr = &h_lds[(bhlf * 4 + bb) * HPAD];
#pragma unroll
      for (int j = 0; j < 4; ++j) {
        f32x4 h4 = *(const f32x4*)(hr + kl * 4 + j * 64);
#pragma unroll
        for (int m = 0; m < 2; ++m) {
          float s = acc2[m * 4 + bb];
          s = fmaf(h4[0], w2r[m][4 + j][0], s); s = fmaf(h4[1], w2r[m][4 + j][1], s);
          s = fmaf(h4[2], w2r[m][4 + j][2], s); s = fmaf(h4[3], w2r[m][4 + j][3], s);
          acc2[m * 4 + bb] = s;
        }
      }
    }

    // ---- consume u (2 chunks/thread, r4 mapping) ----
    {
      u32x4 A, Bc;
      for (;;) {
        sys_ld2_x4(pu0, pu1, A, Bc);
        if (A.z == seq && Bc.z == seq) break;
        __builtin_amdgcn_s_sleep(1);
      }
      int c = tid;
      float2 d0; d0.x = __uint_as_float(A.x); d0.y = __uint_as_float(A.y);
      *(float2*)&u_lds[(c & 7) * HPAD + (c >> 6) * 16 + ((c >> 3) & 7) * 2] = d0;
      c = tid + 512;
      float2 d1; d1.x = __uint_as_float(Bc.x); d1.y = __uint_as_float(Bc.y);
      *(float2*)&u_lds[(c & 7) * HPAD + (c >> 6) * 16 + ((c >> 3) & 7) * 2] = d1;
    }
    __syncthreads();                                 // B1: u_lds ready

    // ---- S2 u-part + reduce ----
#pragma unroll
    for (int bb = 0; bb < 4; ++bb) {
      const float* ur = &u_lds[(bhlf * 4 + bb) * HPAD];
#pragma unroll
      for (int j = 0; j < 4; ++j) {
        f32x4 u4 = *(const f32x4*)(ur + kl * 4 + j * 64);
#pragma unroll
        for (int m = 0; m < 2; ++m) {
          float s = acc2[m * 4 + bb];
          s = fmaf(u4[0], w2r[m][j][0], s); s = fmaf(u4[1], w2r[m][j][1], s);
          s = fmaf(u4[2], w2r[m][j][2], s); s = fmaf(u4[3], w2r[m][j][3], s);
          acc2[m * 4 + bb] = s;
        }
      }
    }
#pragma unroll
    for (int i = 0; i < 8; ++i) {
      float v = acc2[i];
      v += __shfl_xor(v, 1); v += __shfl_xor(v, 2);
      v += __shfl_xor(v, 4); v += __shfl_xor(v, 8);
      acc2[i] = v;
    }
    // ---- S2 epilogue (lane-parallel, precise libm) + publish h ----
    {
      float pre2 = acc2[0];
      pre2 = (kl == 1) ? acc2[1] : pre2;  pre2 = (kl == 2) ? acc2[2] : pre2;
      pre2 = (kl == 3) ? acc2[3] : pre2;  pre2 = (kl == 4) ? acc2[4] : pre2;
      pre2 = (kl == 5) ? acc2[5] : pre2;  pre2 = (kl == 6) ? acc2[6] : pre2;
      pre2 = (kl == 7) ? acc2[7] : pre2;
      int m = kl >> 2;                 // 0=z, 1=h_cand (kl<8)
      int batch = bhlf * 4 + (kl & 3);
      float v2 = pre2 + ((m == 0) ? bz_c : bh_c);
      float gv = (m == 0) ? (1.f / (1.f + expf(-v2))) : tanhf(v2);
      float hcv   = __shfl(gv, kl + 4, 16);
      float hprev = h_lds[batch * HPAD + colg];
      float hn    = gv * hprev + (1.f - gv) * hcv;   // valid on kl<4
      float hnodd = __shfl_xor(hn, 32);
      if (lane < 32 && kl < 4) {
        u32x4 ch;
        ch.x = __float_as_uint(hn); ch.y = __float_as_uint(hnodd);
        ch.z = seq; ch.w = 0u;
        sys_st_x4(h_my + (bhlf * 4 + kl) * 4, ch);
      }
      if (t == T_ - 1 && kl < 4)
        out[(size_t)B_ * T_ * 2 + (size_t)(b0 + batch) * H_ + colg] = hn;  // h_n
    }
    __syncthreads();   // B2: h_lds readers (epi2, out-GEMV) done before overwrite

    // ---- consume h(t+1) ----
    {
      u32x4 A, Bc;
      for (;;) {
        sys_ld2_x4(ph0, ph1, A, Bc);
        if (A.z == seq && Bc.z == seq) break;
        __builtin_amdgcn_s_sleep(1);
      }
      int c = tid;
      float2 d0; d0.x = __uint_as_float(A.x); d0.y = __uint_as_float(A.y);
      *(float2*)&h_lds[(c & 7) * HPAD + (c >> 6) * 16 + ((c >> 3) & 7) * 2] = d0;
      c = tid + 512;
      float2 d1; d1.x = __uint_as_float(Bc.x); d1.y = __uint_as_float(Bc.y);
      *(float2*)&h_lds[(c & 7) * HPAD + (c >> 6) * 16 + ((c >> 3) & 7) * 2] = d1;
    }
    __syncthreads();                                 // B3: h(t+1) ready
  }

  // ---- tail: out[:, T-1] from h(T) (in h_lds) ----
  if (gc == ((T_ - 1) & 15)) {
    f32x4 h4  = *(const f32x4*)&h_lds[w * HPAD + lane * 4];
    f32x4 wo0 = *(const f32x4*)&wo_s[lane * 8];
    f32x4 wo1 = *(const f32x4*)&wo_s[lane * 8 + 4];
    float v0 = h4[0] * wo0[0] + h4[1] * wo0[2] + h4[2] * wo1[0] + h4[3] * wo1[2];
    float v1 = h4[0] * wo0[1] + h4[1] * wo0[3] + h4[2] * wo1[1] + h4[3] * wo1[3];
    v0 += __shfl_xor(v0, 1);  v1 += __shfl_xor(v1, 1);
    v0 += __shfl_xor(v0, 2);  v1 += __shfl_xor(v1, 2);
    v0 += __shfl_xor(v0, 4);  v1 += __shfl_xor(v1, 4);
    v0 += __shfl_xor(v0, 8);  v1 += __shfl_xor(v1, 8);
    v0 += __shfl_xor(v0, 16); v1 += __shfl_xor(v1, 16);
    v0 += __shfl_xor(v0, 32); v1 += __shfl_xor(v1, 32);
    if (lane == 0) {
      float2 o; o.x = v0 + bo0; o.y = v1 + bo1;
      *(float2*)(out + ((size_t)(b0 + w) * T_ + (T_ - 1)) * 2) = o;
    }
  }
}

extern "C" void kernel_launch(void* const* d_in, const int* in_sizes, int n_in,
                              void* d_out, int out_size, void* d_ws, size_t ws_size,
                              hipStream_t stream) {
  (void)in_sizes; (void)n_in; (void)out_size; (void)ws_size;
  const float* x   = (const float*)d_in[0];
  const float* h0  = (const float*)d_in[1];
  const float* Wa  = (const float*)d_in[2];
  const float* ba  = (const float*)d_in[3];
  const float* Wp1 = (const float*)d_in[4];
  const float* bp1 = (const float*)d_in[5];
  const float* Wp2 = (const float*)d_in[6];
  const float* bp2 = (const float*)d_in[7];
  const float* Wz  = (const float*)d_in[8];
  const float* bz  = (const float*)d_in[9];
  const float* Wh  = (const float*)d_in[10];
  const float* bh  = (const float*)d_in[11];
  const float* Wo  = (const float*)d_in[12];
  const float* bo  = (const float*)d_in[13];

  float* out = (float*)d_out;
  char*  ws  = (char*)d_ws;
  unsigned* u_ex = (unsigned*)ws;                 // 16 groups * 16 KB = 256 KB
  unsigned* h_ex = (unsigned*)(ws + 262144);      // 256 KB

  // seqs restart at 1 every replay -> stale chunks from a previous replay
  // would carry valid-looking seqs. Zero both exchange regions each launch.
  hipMemsetAsync(ws, 0, 524288, stream);

  pgjanet_persist<<<dim3(GB * GC), dim3(NTHR), 0, stream>>>(
      x, h0, Wa, ba, Wp1, bp1, Wp2, bp2, Wz, bz, Wh, bh, Wo, bo,
      out, u_ex, h_ex);
}